// Round 14
// baseline (84.268 us; speedup 1.0000x reference)
//
#include <hip/hip_runtime.h>
#include <hip/hip_bf16.h>
#include <stdint.h>

typedef __attribute__((ext_vector_type(8))) short  s16x8;
typedef __attribute__((ext_vector_type(4))) short  s16x4;
typedef __attribute__((ext_vector_type(8))) __bf16 bf16x8;
typedef __attribute__((ext_vector_type(4))) float  f32x4;

#define N_ROWS  32768   // 64 * 512
#define N_CODES 1024
#define DIM     512
#define BK      32      // K-step (elements)

static __device__ __forceinline__ short f2bf(float f) {
    unsigned u = __float_as_uint(f);
    u += 0x7fffu + ((u >> 16) & 1u);   // round-to-nearest-even
    return (short)(u >> 16);
}
static __device__ __forceinline__ float bf2f(short h) {
    return __uint_as_float(((unsigned)(unsigned short)h) << 16);
}

typedef const __attribute__((address_space(1))) uint32_t guint;
typedef __attribute__((address_space(3))) uint32_t luint;
static __device__ __forceinline__ void gl_lds16(const short* g, short* l) {
    __builtin_amdgcn_global_load_lds((guint*)g, (luint*)l, 16, 0, 0);
}

// ---------------- K0: convert W to bf16 + codebook norms ----------------
__global__ void __launch_bounds__(256)
convertW(const float* __restrict__ W, short* __restrict__ Wb,
         float* __restrict__ wnorm) {
    const int lane = threadIdx.x & 63;
    const int code = blockIdx.x * 4 + (threadIdx.x >> 6);
    const float4* wp = (const float4*)(W + (size_t)code * DIM + lane * 8);
    float4 a = wp[0], b = wp[1];
    s16x8 v = { f2bf(a.x), f2bf(a.y), f2bf(a.z), f2bf(a.w),
                f2bf(b.x), f2bf(b.y), f2bf(b.z), f2bf(b.w) };
    *(s16x8*)(Wb + (size_t)code * DIM + lane * 8) = v;
    float s = a.x*a.x + a.y*a.y + a.z*a.z + a.w*a.w
            + b.x*b.x + b.y*b.y + b.z*b.z + b.w*b.w;
    #pragma unroll
    for (int d = 1; d < 64; d <<= 1) s += __shfl_xor(s, d);
    if (lane == 0) wnorm[code] = s;
}

// ---------------- K1: fused convert + GEMM + full-row argmin + row loss ----------------
// Block = 128 rows x ALL 1024 cols. Phase 1: read f32 X rows once (coalesced),
// convert to bf16 into a RESIDENT 128KB A-LDS with slot-XOR layout
// (phys_slot = slot ^ (row&7); we control both write and read -> free swizzle).
// Phase 1b: xnorm[128] from As readback (bf16-sourced; loss bias ~1e-7).
// Phase 2: 8 col-tiles x 16 K-steps; B staged per step via the R7-verified
// 0-conflict global_load_lds path (2 loads/thread, dbuf, pre-swizzled src,
// linear dest, fq read). A read from resident LDS (0 staging). Running
// per-lane min-key across all tiles; final cross-wave merge in LDS; one
// f32 partial per block. No Xb, no keys array, no reduce_loss kernel.
__global__ void __launch_bounds__(256)
fused_gemm(const float* __restrict__ X, const short* __restrict__ Wb,
           const float* __restrict__ wnorm, float* __restrict__ partial) {
    __shared__ __align__(16) short As[128 * 512];      // 128 KB, resident
    __shared__ __align__(16) short Bs[2][128 * BK];    // 16 KB dbuf
    __shared__ float xnBuf[128];
    __shared__ float wsumArr[4];

    const int tid  = threadIdx.x;
    const int lane = tid & 63;
    const int wave = tid >> 6;
    const int wr = wave >> 1, wc = wave & 1;
    const int lr = lane & 15, kg = lane >> 4;
    const int rowBase = blockIdx.x * 128;

    // ---- Phase 1: f32 X -> bf16 As (one pass, coalesced float4) ----
    {
        const float4* X4 = (const float4*)(X + (size_t)rowBase * DIM);
        #pragma unroll 8
        for (int p = 0; p < 64; ++p) {
            const int f = p * 256 + tid;          // flat float4 idx [0,16384)
            float4 v = X4[f];
            const int row = f >> 7, c4 = f & 127; // 128 float4 per row
            const int slot = (c4 >> 1) ^ (row & 7);
            s16x4 b = { f2bf(v.x), f2bf(v.y), f2bf(v.z), f2bf(v.w) };
            *(s16x4*)&As[row * 512 + slot * 8 + (c4 & 1) * 4] = b;
        }
    }
    // B staging (R7-verified form): rows tid>>2 (+64), phys slot tid&3,
    // source slot pre-swizzled by (row>>1)&3 = (tid>>3)&3, linear dest.
    const int ssw = ((tid & 3) ^ ((tid >> 3) & 3)) * 8;
    const short* bS = Wb + (size_t)(tid >> 2) * DIM + ssw;
#define STAGE_B(buf, cb, t) do {                                              \
    gl_lds16(bS + (size_t)(cb) * DIM + (t) * BK,        &Bs[buf][tid * 8]);   \
    gl_lds16(bS + (size_t)((cb) + 64) * DIM + (t) * BK, &Bs[buf][tid * 8 + 2048]); \
  } while (0)

    STAGE_B(0, 0, 0);
    __syncthreads();   // conversion visible to all + B(0,0) landed

    // ---- Phase 1b: xnorm from As (2 threads/row) ----
    {
        const int r = tid >> 1, hf = tid & 1;
        float s = 0.f;
        #pragma unroll
        for (int j = 0; j < 32; ++j) {
            s16x8 v = *(const s16x8*)&As[r * 512 + (((hf * 32 + j) ^ (r & 7))) * 8];
            #pragma unroll
            for (int e = 0; e < 8; ++e) { float f = bf2f(v[e]); s += f * f; }
        }
        s += __shfl_xor(s, 1);
        if (hf == 0) xnBuf[r] = s;
    }

    // ---- Phase 2: 8 col-tiles x 16 K-steps ----
    f32x4 acc[4][4];
    #pragma unroll
    for (int m = 0; m < 4; ++m)
        #pragma unroll
        for (int n = 0; n < 4; ++n) acc[m][n] = (f32x4)0.f;
    uint32_t runKey[4][4];
    #pragma unroll
    for (int m = 0; m < 4; ++m)
        #pragma unroll
        for (int r = 0; r < 4; ++r) runKey[m][r] = 0xFFFFFFFFu;

    const int fq = (kg ^ ((lr >> 1) & 3)) * 8;   // B swizzled read slot
    const int aRowBase = (wr * 64 + lr) * 512;

    for (int ct = 0; ct < 8; ++ct) {
        const int colBase = ct * 128;
        for (int t = 0; t < 16; ++t) {
            const int cur = (ct * 16 + t) & 1;
            if (t < 15)      STAGE_B(cur ^ 1, colBase, t + 1);
            else if (ct < 7) STAGE_B(cur ^ 1, colBase + 128, 0);
            bf16x8 aF[4], bF[4];
            #pragma unroll
            for (int m = 0; m < 4; ++m)
                aF[m] = __builtin_bit_cast(bf16x8, *(const s16x8*)
                    &As[aRowBase + m * 16 * 512 + ((t * 4 + kg) ^ (lr & 7)) * 8]);
            #pragma unroll
            for (int n = 0; n < 4; ++n)
                bF[n] = __builtin_bit_cast(bf16x8, *(const s16x8*)
                    &Bs[cur][(wc * 64 + n * 16 + lr) * BK + fq]);
            #pragma unroll
            for (int m = 0; m < 4; ++m)
                #pragma unroll
                for (int n = 0; n < 4; ++n)
                    acc[m][n] = __builtin_amdgcn_mfma_f32_16x16x32_bf16(
                        aF[m], bF[n], acc[m][n], 0, 0, 0);
            __syncthreads();   // drains vmcnt -> staged buffer ready
        }
        // fold this col-tile's scores into the running min-keys
        #pragma unroll
        for (int n = 0; n < 4; ++n) {
            const int wcol = colBase + wc * 64 + n * 16 + lr;
            const float wn = wnorm[wcol];
            #pragma unroll
            for (int m = 0; m < 4; ++m)
                #pragma unroll
                for (int r = 0; r < 4; ++r) {
                    float sc = wn - 2.0f * acc[m][n][r];
                    uint32_t u = __float_as_uint(sc);
                    u = (u & 0x80000000u) ? ~u : (u | 0x80000000u);  // sortable
                    runKey[m][r] = min(runKey[m][r], (u & ~1023u) | (uint32_t)wcol);
                }
        }
        #pragma unroll
        for (int m = 0; m < 4; ++m)
            #pragma unroll
            for (int n = 0; n < 4; ++n) acc[m][n] = (f32x4)0.f;
    }
#undef STAGE_B

    // ---- Final: 16-lane reduce, cross-wave (wc) merge, row loss sum ----
    uint32_t myKey[4][4];
    #pragma unroll
    for (int m = 0; m < 4; ++m)
        #pragma unroll
        for (int r = 0; r < 4; ++r) {
            uint32_t k = runKey[m][r];
            #pragma unroll
            for (int d = 1; d < 16; d <<= 1)
                k = min(k, (uint32_t)__shfl_xor((int)k, d));
            myKey[m][r] = k;
        }
    uint32_t* keyX = (uint32_t*)&Bs[0][0];   // Bs dead; reuse as scratch
    __syncthreads();
    if (wc == 1 && lr == 0) {
        #pragma unroll
        for (int m = 0; m < 4; ++m)
            #pragma unroll
            for (int r = 0; r < 4; ++r)
                keyX[wr * 64 + m * 16 + kg * 4 + r] = myKey[m][r];
    }
    __syncthreads();
    float blockSum = 0.f;
    if (wc == 0 && lr == 0) {
        #pragma unroll
        for (int m = 0; m < 4; ++m)
            #pragma unroll
            for (int r = 0; r < 4; ++r) {
                const int row = wr * 64 + m * 16 + kg * 4 + r;
                uint32_t k = min(myKey[m][r], keyX[row]);
                uint32_t sb = k & ~1023u;
                float sc = (sb & 0x80000000u) ? __uint_as_float(sb ^ 0x80000000u)
                                              : __uint_as_float(~sb);
                blockSum += xnBuf[row] + sc;   // ||x||^2 + (||w||^2 - 2 x.w)
            }
    }
    #pragma unroll
    for (int d = 1; d < 64; d <<= 1) blockSum += __shfl_xor(blockSum, d);
    if (lane == 0) wsumArr[wave] = blockSum;
    __syncthreads();
    if (tid == 0)
        partial[blockIdx.x] = wsumArr[0] + wsumArr[1] + wsumArr[2] + wsumArr[3];
}

// ---------------- K2: final mean over 256 partials (double accum) ----------------
__global__ void __launch_bounds__(256)
finalize(const float* __restrict__ partial, float* __restrict__ out) {
    __shared__ double sm[256];
    sm[threadIdx.x] = (double)partial[threadIdx.x];
    __syncthreads();
    for (int st = 128; st > 0; st >>= 1) {
        if (threadIdx.x < st) sm[threadIdx.x] += sm[threadIdx.x + st];
        __syncthreads();
    }
    if (threadIdx.x == 0)
        out[0] = (float)(sm[0] / (double)((size_t)N_ROWS * DIM));
}

extern "C" void kernel_launch(void* const* d_in, const int* in_sizes, int n_in,
                              void* d_out, int out_size, void* d_ws, size_t ws_size,
                              hipStream_t stream) {
    const float* X = (const float*)d_in[0];   // [32768][512]
    const float* W = (const float*)d_in[1];   // [1024][512]
    char* ws = (char*)d_ws;
    short*  Wb      = (short*)ws;                    // 1 MB @ 0
    float*  wnorm   = (float*)(ws + 1048576);        // 4 KB
    float*  partial = (float*)(ws + 1052672);        // 1 KB
    float*  out     = (float*)d_out;

    convertW<<<N_CODES / 4, 256, 0, stream>>>(W, Wb, wnorm);
    fused_gemm<<<N_ROWS / 128, 256, 0, stream>>>(X, Wb, wnorm, partial);
    finalize<<<1, 256, 0, stream>>>(partial, out);
}

// Round 15
// 68.458 us; speedup vs baseline: 1.2310x; 1.2310x over previous
//
#include <hip/hip_runtime.h>
#include <hip/hip_bf16.h>
#include <stdint.h>

typedef __attribute__((ext_vector_type(8))) short  s16x8;
typedef __attribute__((ext_vector_type(8))) __bf16 bf16x8;
typedef __attribute__((ext_vector_type(4))) float  f32x4;

#define N_ROWS  32768   // 64 * 512
#define N_CODES 1024
#define DIM     512
#define BK      32      // K-tile (shorts)
#define NT      (DIM / BK)   // 16 K-steps

static __device__ __forceinline__ short f2bf(float f) {
    unsigned u = __float_as_uint(f);
    u += 0x7fffu + ((u >> 16) & 1u);   // round-to-nearest-even
    return (short)(u >> 16);
}

typedef const __attribute__((address_space(1))) uint32_t guint;
typedef __attribute__((address_space(3))) uint32_t luint;
static __device__ __forceinline__ void gl_lds16(const short* g, short* l) {
    __builtin_amdgcn_global_load_lds((guint*)g, (luint*)l, 16, 0, 0);
}

// ---------------- K0: convert X and W to bf16 + norms (single launch) ----------------
// Blocks [0,8192) handle X (4 rows each); blocks [8192,8256) handle W
// (4 codes each). Both paths are pure BW-floor passes; fusing saves a
// launch gap. Wave-per-row, float4 loads, shfl-reduce norm.
__global__ void __launch_bounds__(256)
convertXW(const float* __restrict__ X, const float* __restrict__ W,
          short* __restrict__ Xb, short* __restrict__ Wb,
          float* __restrict__ xnorm, float* __restrict__ wnorm) {
    const int lane = threadIdx.x & 63;
    const int sub  = threadIdx.x >> 6;
    const float* src; short* dst; float* nrm; int row;
    if (blockIdx.x < 8192) {
        row = blockIdx.x * 4 + sub;
        src = X; dst = Xb; nrm = xnorm;
    } else {
        row = (blockIdx.x - 8192) * 4 + sub;
        src = W; dst = Wb; nrm = wnorm;
    }
    const float4* p = (const float4*)(src + (size_t)row * DIM + lane * 8);
    float4 a = p[0], b = p[1];
    s16x8 v = { f2bf(a.x), f2bf(a.y), f2bf(a.z), f2bf(a.w),
                f2bf(b.x), f2bf(b.y), f2bf(b.z), f2bf(b.w) };
    *(s16x8*)(dst + (size_t)row * DIM + lane * 8) = v;
    float s = a.x*a.x + a.y*a.y + a.z*a.z + a.w*a.w
            + b.x*b.x + b.y*b.y + b.z*b.z + b.w*b.w;
    #pragma unroll
    for (int d = 1; d < 64; d <<= 1) s += __shfl_xor(s, d);
    if (lane == 0) nrm[row] = s;
}

// ---------------- K1: bf16 MFMA GEMM (16x16x32) + per-tile argmin ----------------
// R10's exact kernel (best measured: 53.2us, 0 bank conflicts, FETCH 20.6MB).
// 128x256 block, 4 waves (2x2), wave tile 64x128 (32 MFMA / 12 ds_reads).
// Triple-buffered LDS, counted vmcnt(6) gate (never 0 until tail).
// 0-conflict layout: frag reads span 16 rows/instr (lr=lane&15), slot XOR
// phys = kg ^ ((row>>1)&3) applied both-sides (pre-swizzled global source,
// linear gl_lds dest, swizzled ds_read). XCD row-chunk swizzle: XCD x owns
// Xb rows [x*4096, x*4096+4096) = 4MB = its L2. Packed-key argmin epilogue.
__global__ void __launch_bounds__(256, 2)
gemm_argmin(const short* __restrict__ Xb, const short* __restrict__ Wb,
            const float* __restrict__ wnorm, uint32_t* __restrict__ keys) {
    __shared__ __align__(16) short As[3][128 * BK];   // 24 KB
    __shared__ __align__(16) short Bs[3][256 * BK];   // 48 KB

    const int tid  = threadIdx.x;
    const int lane = tid & 63;
    const int wave = tid >> 6;
    const int wr = wave >> 1, wc = wave & 1;
    const int lr = lane & 15, kg = lane >> 4;

    // bid = xcd + 8*colBlk(0..3) + 32*rowLocal(0..31); grid 1024.
    const int bid = blockIdx.x;
    const int colBase = ((bid >> 3) & 3) * 256;
    const int rowBase = ((bid & 7) * 32 + (bid >> 5)) * 128;

    const int ssw = ((tid & 3) ^ ((tid >> 3) & 3)) * 8;
    const short* aS = Xb + (size_t)(rowBase + (tid >> 2)) * DIM + ssw;
    const short* bS = Wb + (size_t)(colBase + (tid >> 2)) * DIM + ssw;

#define STAGE(buf, t) do {                                                    \
    gl_lds16(aS + (t) * BK,            &As[buf][tid * 8]);                    \
    gl_lds16(aS + 64*DIM + (t) * BK,   &As[buf][tid * 8 + 2048]);             \
    gl_lds16(bS + (t) * BK,            &Bs[buf][tid * 8]);                    \
    gl_lds16(bS + 64*DIM + (t) * BK,   &Bs[buf][tid * 8 + 2048]);             \
    gl_lds16(bS + 128*DIM + (t) * BK,  &Bs[buf][tid * 8 + 4096]);             \
    gl_lds16(bS + 192*DIM + (t) * BK,  &Bs[buf][tid * 8 + 6144]);             \
  } while (0)

    f32x4 acc[4][8];
    #pragma unroll
    for (int m = 0; m < 4; ++m)
        #pragma unroll
        for (int n = 0; n < 8; ++n) acc[m][n] = (f32x4)0.f;

    const int fq = (kg ^ ((lr >> 1) & 3)) * 8;   // swizzled read slot (shorts)

    STAGE(0, 0);
    STAGE(1, 1);
    asm volatile("s_waitcnt vmcnt(6)" ::: "memory");
    __builtin_amdgcn_s_barrier();

    #pragma unroll
    for (int t = 0; t < NT; ++t) {
        const int cur = t % 3;
        if (t + 2 < NT) STAGE((t + 2) % 3, t + 2);   // depth-2 prefetch
        bf16x8 aF[4], bF[8];
        #pragma unroll
        for (int m = 0; m < 4; ++m)
            aF[m] = __builtin_bit_cast(bf16x8,
                *(const s16x8*)&As[cur][(wr*64 + m*16 + lr) * BK + fq]);
        #pragma unroll
        for (int n = 0; n < 8; ++n)
            bF[n] = __builtin_bit_cast(bf16x8,
                *(const s16x8*)&Bs[cur][(wc*128 + n*16 + lr) * BK + fq]);
        #pragma unroll
        for (int m = 0; m < 4; ++m)
            #pragma unroll
            for (int n = 0; n < 8; ++n)
                acc[m][n] = __builtin_amdgcn_mfma_f32_16x16x32_bf16(
                    aF[m], bF[n], acc[m][n], 0, 0, 0);
        if (t < NT - 2) {
            asm volatile("s_waitcnt vmcnt(6)" ::: "memory");
            __builtin_amdgcn_s_barrier();
        } else if (t == NT - 2) {
            asm volatile("s_waitcnt vmcnt(0)" ::: "memory");
            __builtin_amdgcn_s_barrier();
        }
    }
#undef STAGE

    // Epilogue: score = wnorm[col] - 2*dot, packed sortable u32 (col in low
    // 10 bits, tie-break = lowest col). 2 chunk-groups of 4 n-frags each.
    float wn[8]; int wcol[8];
    #pragma unroll
    for (int n = 0; n < 8; ++n) {
        wcol[n] = colBase + wc*128 + n*16 + lr;
        wn[n] = wnorm[wcol[n]];
    }
    #pragma unroll
    for (int m = 0; m < 4; ++m) {
        #pragma unroll
        for (int r = 0; r < 4; ++r) {
            #pragma unroll
            for (int g = 0; g < 2; ++g) {
                uint32_t best = 0xFFFFFFFFu;
                #pragma unroll
                for (int j = 0; j < 4; ++j) {
                    const int n = g * 4 + j;
                    float sc = wn[n] - 2.0f * acc[m][n][r];
                    uint32_t u = __float_as_uint(sc);
                    u = (u & 0x80000000u) ? ~u : (u | 0x80000000u);  // sortable
                    uint32_t key = (u & ~1023u) | (uint32_t)wcol[n];
                    best = min(best, key);
                }
                #pragma unroll
                for (int d = 1; d < 16; d <<= 1)
                    best = min(best, (uint32_t)__shfl_xor((int)best, d));
                if (lr == 0) {
                    const int row = rowBase + wr*64 + m*16 + kg*4 + r;
                    keys[(size_t)row * 16 + (colBase >> 6) + wc*2 + g] = best;
                }
            }
        }
    }
}

// ---------------- K2: min over 16 chunk keys + xnorm -> block partial ----------------
__global__ void __launch_bounds__(256)
reduce_loss(const uint32_t* __restrict__ keys, const float* __restrict__ xnorm,
            float* __restrict__ partial) {
    __shared__ float sm[256];
    const int row = blockIdx.x * 256 + threadIdx.x;
    const uint4* kp = (const uint4*)(keys + (size_t)row * 16);
    uint4 k0 = kp[0], k1 = kp[1], k2 = kp[2], k3 = kp[3];
    uint32_t mk = min(min(min(k0.x, k0.y), min(k0.z, k0.w)),
                      min(min(k1.x, k1.y), min(k1.z, k1.w)));
    mk = min(mk, min(min(min(k2.x, k2.y), min(k2.z, k2.w)),
                     min(min(k3.x, k3.y), min(k3.z, k3.w))));
    uint32_t sb = mk & ~1023u;
    float sc = (sb & 0x80000000u) ? __uint_as_float(sb ^ 0x80000000u)
                                  : __uint_as_float(~sb);
    sm[threadIdx.x] = xnorm[row] + sc;   // ||x||^2 + (||w||^2 - 2 x.w)
    __syncthreads();
    for (int st = 128; st > 0; st >>= 1) {
        if (threadIdx.x < st) sm[threadIdx.x] += sm[threadIdx.x + st];
        __syncthreads();
    }
    if (threadIdx.x == 0) partial[blockIdx.x] = sm[0];
}

// ---------------- K3: final mean over 128 partials (double accum) ----------------
__global__ void __launch_bounds__(128)
finalize(const float* __restrict__ partial, float* __restrict__ out) {
    __shared__ double sm[128];
    sm[threadIdx.x] = (double)partial[threadIdx.x];
    __syncthreads();
    for (int st = 64; st > 0; st >>= 1) {
        if (threadIdx.x < st) sm[threadIdx.x] += sm[threadIdx.x + st];
        __syncthreads();
    }
    if (threadIdx.x == 0)
        out[0] = (float)(sm[0] / (double)((size_t)N_ROWS * DIM));
}

extern "C" void kernel_launch(void* const* d_in, const int* in_sizes, int n_in,
                              void* d_out, int out_size, void* d_ws, size_t ws_size,
                              hipStream_t stream) {
    const float* X = (const float*)d_in[0];   // [32768][512]
    const float* W = (const float*)d_in[1];   // [1024][512]
    char* ws = (char*)d_ws;
    short*    Xb      = (short*)ws;                          // 32 MB @ 0
    short*    Wb      = (short*)(ws + 33554432);             // 1 MB
    float*    wnorm   = (float*)(ws + 34603008);             // 4 KB
    float*    xnorm   = (float*)(ws + 34607104);             // 128 KB
    uint32_t* keys    = (uint32_t*)(ws + 34738176);          // 2 MB
    float*    partial = (float*)(ws + 36835328);             // 512 B
    float*    out     = (float*)d_out;

    convertXW<<<8192 + N_CODES / 4, 256, 0, stream>>>(X, W, Xb, Wb, xnorm, wnorm);
    gemm_argmin<<<1024, 256, 0, stream>>>(Xb, Wb, wnorm, keys);
    reduce_loss<<<N_ROWS / 256, 256, 0, stream>>>(keys, xnorm, partial);
    finalize<<<1, 128, 0, stream>>>(partial, out);
}

// Round 16
// 52.939 us; speedup vs baseline: 1.5918x; 1.2931x over previous
//
#include <hip/hip_runtime.h>
#include <hip/hip_bf16.h>
#include <stdint.h>

typedef __attribute__((ext_vector_type(4))) int i32x4;

#define N_ROWS  32768   // 64 * 512
#define N_CODES 1024
#define DIM     512
#define BK      64      // K-tile (i8 elements = bytes)
#define NT      (DIM / BK)   // 8 K-steps

typedef const __attribute__((address_space(1))) uint32_t guint;
typedef __attribute__((address_space(3))) uint32_t luint;
static __device__ __forceinline__ void gl_lds16(const char* g, char* l) {
    __builtin_amdgcn_global_load_lds((guint*)g, (luint*)l, 16, 0, 0);
}

static __device__ __forceinline__ int q8(float v) {
    int q = __float2int_rn(v * 32.0f);
    return max(-127, min(127, q));
}

// ---------------- K0: quantize X and W to i8 (scale 32) + exact f32 norms ----------------
// Blocks [0,8192) -> X rows; [8192,8448) -> W rows. Wave per row, float4
// loads, 8 i8 out per lane (uint2 store), shfl-reduce exact norm.
__global__ void __launch_bounds__(256)
convertXW(const float* __restrict__ X, const float* __restrict__ W,
          char* __restrict__ Xq, char* __restrict__ Wq,
          float* __restrict__ xnorm, float* __restrict__ wnorm) {
    const int lane = threadIdx.x & 63;
    const int sub  = threadIdx.x >> 6;
    const float* src; char* dst; float* nrm; int row;
    if (blockIdx.x < 8192) {
        row = blockIdx.x * 4 + sub;
        src = X; dst = Xq; nrm = xnorm;
    } else {
        row = (blockIdx.x - 8192) * 4 + sub;
        src = W; dst = Wq; nrm = wnorm;
    }
    const float4* p = (const float4*)(src + (size_t)row * DIM + lane * 8);
    float4 a = p[0], b = p[1];
    uint32_t lo = (uint32_t)(q8(a.x) & 0xFF)
                | ((uint32_t)(q8(a.y) & 0xFF) << 8)
                | ((uint32_t)(q8(a.z) & 0xFF) << 16)
                | ((uint32_t)(q8(a.w) & 0xFF) << 24);
    uint32_t hi = (uint32_t)(q8(b.x) & 0xFF)
                | ((uint32_t)(q8(b.y) & 0xFF) << 8)
                | ((uint32_t)(q8(b.z) & 0xFF) << 16)
                | ((uint32_t)(q8(b.w) & 0xFF) << 24);
    *(uint2*)(dst + (size_t)row * DIM + lane * 8) = make_uint2(lo, hi);
    float s = a.x*a.x + a.y*a.y + a.z*a.z + a.w*a.w
            + b.x*b.x + b.y*b.y + b.z*b.z + b.w*b.w;
    #pragma unroll
    for (int d = 1; d < 64; d <<= 1) s += __shfl_xor(s, d);
    if (lane == 0) nrm[row] = s;
}

// ---------------- K1: i8 MFMA GEMM (16x16x64) + per-tile argmin ----------------
// R10's exact structure (best measured 53.2us) with i8 data: 128x256 block,
// 4 waves (2x2), wave tile 64x128 (32 MFMA / 12 b128 reads per K=64 step,
// 8 steps). Triple-buffered LDS, counted vmcnt(6). LDS geometry is R7's
// measured-0-conflict form (64B rows, 4x16B slots, slot XOR (row>>1)&3
// both-sides: pre-swizzled global source, linear gl_lds dest, swizzled read).
// Exact i32 accumulation; score = wnorm - dot_int/512 in f32. XCD row-chunk
// swizzle: XCD x owns Xq rows [x*4096, x*4096+4096) = 2MB (L2-resident).
__global__ void __launch_bounds__(256, 2)
gemm_argmin(const char* __restrict__ Xq, const char* __restrict__ Wq,
            const float* __restrict__ wnorm, uint32_t* __restrict__ keys) {
    __shared__ __align__(16) char As[3][128 * BK];   // 24 KB
    __shared__ __align__(16) char Bs[3][256 * BK];   // 48 KB

    const int tid  = threadIdx.x;
    const int lane = tid & 63;
    const int wave = tid >> 6;
    const int wr = wave >> 1, wc = wave & 1;
    const int lr = lane & 15, kg = lane >> 4;

    // bid = xcd + 8*colBlk(0..3) + 32*rowLocal(0..31); grid 1024.
    const int bid = blockIdx.x;
    const int colBase = ((bid >> 3) & 3) * 256;
    const int rowBase = ((bid & 7) * 32 + (bid >> 5)) * 128;

    // staging: thread -> row (tid>>2) (+64/+128/+192), phys slot (tid&3);
    // source slot pre-swizzled by (row>>1)&3 = (tid>>3)&3. LDS dest linear.
    const int ssw = ((tid & 3) ^ ((tid >> 3) & 3)) * 16;
    const char* aS = Xq + (size_t)(rowBase + (tid >> 2)) * DIM + ssw;
    const char* bS = Wq + (size_t)(colBase + (tid >> 2)) * DIM + ssw;

#define STAGE(buf, t) do {                                                    \
    gl_lds16(aS + (t) * BK,            &As[buf][tid * 16]);                   \
    gl_lds16(aS + 64*DIM + (t) * BK,   &As[buf][tid * 16 + 4096]);            \
    gl_lds16(bS + (t) * BK,            &Bs[buf][tid * 16]);                   \
    gl_lds16(bS + 64*DIM + (t) * BK,   &Bs[buf][tid * 16 + 4096]);            \
    gl_lds16(bS + 128*DIM + (t) * BK,  &Bs[buf][tid * 16 + 8192]);            \
    gl_lds16(bS + 192*DIM + (t) * BK,  &Bs[buf][tid * 16 + 12288]);           \
  } while (0)

    i32x4 acc[4][8];
    #pragma unroll
    for (int m = 0; m < 4; ++m)
        #pragma unroll
        for (int n = 0; n < 8; ++n) acc[m][n] = (i32x4)0;

    const int fq = (kg ^ ((lr >> 1) & 3)) * 16;   // swizzled read slot (bytes)

    STAGE(0, 0);
    STAGE(1, 1);
    asm volatile("s_waitcnt vmcnt(6)" ::: "memory");
    __builtin_amdgcn_s_barrier();

    #pragma unroll
    for (int t = 0; t < NT; ++t) {
        const int cur = t % 3;
        if (t + 2 < NT) STAGE((t + 2) % 3, t + 2);   // depth-2 prefetch
        i32x4 aF[4], bF[8];
        #pragma unroll
        for (int m = 0; m < 4; ++m)
            aF[m] = *(const i32x4*)&As[cur][(wr*64 + m*16 + lr) * BK + fq];
        #pragma unroll
        for (int n = 0; n < 8; ++n)
            bF[n] = *(const i32x4*)&Bs[cur][(wc*128 + n*16 + lr) * BK + fq];
        #pragma unroll
        for (int m = 0; m < 4; ++m)
            #pragma unroll
            for (int n = 0; n < 8; ++n)
                acc[m][n] = __builtin_amdgcn_mfma_i32_16x16x64_i8(
                    aF[m], bF[n], acc[m][n], 0, 0, 0);
        if (t < NT - 2) {
            asm volatile("s_waitcnt vmcnt(6)" ::: "memory");
            __builtin_amdgcn_s_barrier();
        } else if (t == NT - 2) {
            asm volatile("s_waitcnt vmcnt(0)" ::: "memory");
            __builtin_amdgcn_s_barrier();
        }
    }
#undef STAGE

    // Epilogue: dot = acc/1024 (scale 32 each side); score = wnorm - 2*dot
    // = wnorm - acc/512. Packed sortable u32, col in low 10 bits.
    float wn[8]; int wcol[8];
    #pragma unroll
    for (int n = 0; n < 8; ++n) {
        wcol[n] = colBase + wc*128 + n*16 + lr;
        wn[n] = wnorm[wcol[n]];
    }
    #pragma unroll
    for (int m = 0; m < 4; ++m) {
        #pragma unroll
        for (int r = 0; r < 4; ++r) {
            #pragma unroll
            for (int g = 0; g < 2; ++g) {
                uint32_t best = 0xFFFFFFFFu;
                #pragma unroll
                for (int j = 0; j < 4; ++j) {
                    const int n = g * 4 + j;
                    float sc = wn[n] - (float)acc[m][n][r] * 0.001953125f;
                    uint32_t u = __float_as_uint(sc);
                    u = (u & 0x80000000u) ? ~u : (u | 0x80000000u);  // sortable
                    uint32_t key = (u & ~1023u) | (uint32_t)wcol[n];
                    best = min(best, key);
                }
                #pragma unroll
                for (int d = 1; d < 16; d <<= 1)
                    best = min(best, (uint32_t)__shfl_xor((int)best, d));
                if (lr == 0) {
                    const int row = rowBase + wr*64 + m*16 + kg*4 + r;
                    keys[(size_t)row * 16 + (colBase >> 6) + wc*2 + g] = best;
                }
            }
        }
    }
}

// ---------------- K2: min over 16 chunk keys + xnorm -> block partial ----------------
__global__ void __launch_bounds__(256)
reduce_loss(const uint32_t* __restrict__ keys, const float* __restrict__ xnorm,
            float* __restrict__ partial) {
    __shared__ float sm[256];
    const int row = blockIdx.x * 256 + threadIdx.x;
    const uint4* kp = (const uint4*)(keys + (size_t)row * 16);
    uint4 k0 = kp[0], k1 = kp[1], k2 = kp[2], k3 = kp[3];
    uint32_t mk = min(min(min(k0.x, k0.y), min(k0.z, k0.w)),
                      min(min(k1.x, k1.y), min(k1.z, k1.w)));
    mk = min(mk, min(min(min(k2.x, k2.y), min(k2.z, k2.w)),
                     min(min(k3.x, k3.y), min(k3.z, k3.w))));
    uint32_t sb = mk & ~1023u;
    float sc = (sb & 0x80000000u) ? __uint_as_float(sb ^ 0x80000000u)
                                  : __uint_as_float(~sb);
    sm[threadIdx.x] = xnorm[row] + sc;   // ||x||^2 + (||w||^2 - 2 x.w)
    __syncthreads();
    for (int st = 128; st > 0; st >>= 1) {
        if (threadIdx.x < st) sm[threadIdx.x] += sm[threadIdx.x + st];
        __syncthreads();
    }
    if (threadIdx.x == 0) partial[blockIdx.x] = sm[0];
}

// ---------------- K3: final mean over 128 partials (double accum) ----------------
__global__ void __launch_bounds__(128)
finalize(const float* __restrict__ partial, float* __restrict__ out) {
    __shared__ double sm[128];
    sm[threadIdx.x] = (double)partial[threadIdx.x];
    __syncthreads();
    for (int st = 64; st > 0; st >>= 1) {
        if (threadIdx.x < st) sm[threadIdx.x] += sm[threadIdx.x + st];
        __syncthreads();
    }
    if (threadIdx.x == 0)
        out[0] = (float)(sm[0] / (double)((size_t)N_ROWS * DIM));
}

extern "C" void kernel_launch(void* const* d_in, const int* in_sizes, int n_in,
                              void* d_out, int out_size, void* d_ws, size_t ws_size,
                              hipStream_t stream) {
    const float* X = (const float*)d_in[0];   // [32768][512]
    const float* W = (const float*)d_in[1];   // [1024][512]
    char* ws = (char*)d_ws;
    char*     Xq      = ws;                                  // 16 MB @ 0
    char*     Wq      = ws + 16777216;                       // 512 KB
    float*    wnorm   = (float*)(ws + 17301504);             // 4 KB
    float*    xnorm   = (float*)(ws + 17305600);             // 128 KB
    uint32_t* keys    = (uint32_t*)(ws + 17436672);          // 2 MB
    float*    partial = (float*)(ws + 19533824);             // 512 B
    float*    out     = (float*)d_out;

    convertXW<<<8192 + N_CODES / 4, 256, 0, stream>>>(X, W, Xq, Wq, xnorm, wnorm);
    gemm_argmin<<<1024, 256, 0, stream>>>(Xq, Wq, wnorm, keys);
    reduce_loss<<<N_ROWS / 256, 256, 0, stream>>>(keys, xnorm, partial);
    finalize<<<1, 128, 0, stream>>>(partial, out);
}